// Round 1
// baseline (490.540 us; speedup 1.0000x reference)
//
#include <hip/hip_runtime.h>
#include <hip/hip_bf16.h>

#define ALPHA 0.2f

constexpr int N    = 8192;
constexpr int FIN  = 512;
constexpr int FOUT = 64;
constexpr int NSPLIT = 4;
constexpr int JCHUNK = N / NSPLIT;   // 2048

typedef __attribute__((ext_vector_type(8))) short short8;
typedef __attribute__((ext_vector_type(4))) float f32x4;

// ---------------------------------------------------------------------------
// Kernel 1: h = input @ W (fp32), fused:
//   - s1 = h @ a[:64], s2 = h @ a[64:]  (wave butterfly reduction)
//   - hbT = h^T in bf16 (64 x N), via LDS transpose (B-operand feed for MFMA)
// Each block: 16 rows of h, 256 threads (wave g owns rows 4g..4g+3, lane=col).
// ---------------------------------------------------------------------------
__global__ __launch_bounds__(256) void k1_proj(
    const float* __restrict__ input, const float* __restrict__ W,
    const float* __restrict__ a, __hip_bfloat16* __restrict__ hbT,
    float* __restrict__ s1, float* __restrict__ s2)
{
    __shared__ __hip_bfloat16 tile[16][64];
    const int tid  = threadIdx.x;
    const int col  = tid & 63;
    const int g    = tid >> 6;
    const int rbase = blockIdx.x * 16;

    float acc[4] = {0.f, 0.f, 0.f, 0.f};
    const float* in0 = input + (size_t)(rbase + g * 4) * FIN;

    for (int k = 0; k < FIN; k += 4) {
        const float w0 = W[(k + 0) * FOUT + col];
        const float w1 = W[(k + 1) * FOUT + col];
        const float w2 = W[(k + 2) * FOUT + col];
        const float w3 = W[(k + 3) * FOUT + col];
        const float4 x0 = *(const float4*)(in0 + 0 * FIN + k);
        const float4 x1 = *(const float4*)(in0 + 1 * FIN + k);
        const float4 x2 = *(const float4*)(in0 + 2 * FIN + k);
        const float4 x3 = *(const float4*)(in0 + 3 * FIN + k);
        acc[0] = fmaf(x0.w, w3, fmaf(x0.z, w2, fmaf(x0.y, w1, fmaf(x0.x, w0, acc[0]))));
        acc[1] = fmaf(x1.w, w3, fmaf(x1.z, w2, fmaf(x1.y, w1, fmaf(x1.x, w0, acc[1]))));
        acc[2] = fmaf(x2.w, w3, fmaf(x2.z, w2, fmaf(x2.y, w1, fmaf(x2.x, w0, acc[2]))));
        acc[3] = fmaf(x3.w, w3, fmaf(x3.z, w2, fmaf(x3.y, w1, fmaf(x3.x, w0, acc[3]))));
    }

    const float a1c = a[col];
    const float a2c = a[FOUT + col];
    #pragma unroll
    for (int q = 0; q < 4; ++q) {
        float r1 = acc[q] * a1c;
        float r2 = acc[q] * a2c;
        #pragma unroll
        for (int off = 32; off >= 1; off >>= 1) {
            r1 += __shfl_xor(r1, off, 64);
            r2 += __shfl_xor(r2, off, 64);
        }
        if (col == 0) {
            s1[rbase + g * 4 + q] = r1;
            s2[rbase + g * 4 + q] = r2;
        }
        tile[g * 4 + q][col] = __float2bfloat16(acc[q]);
    }
    __syncthreads();

    // transpose write: hbT[c][rbase + part*4 + u], 8B stores
    const int c = tid >> 2, part = tid & 3;
    unsigned short v[4];
    #pragma unroll
    for (int u = 0; u < 4; ++u) {
        __hip_bfloat16 hv = tile[part * 4 + u][c];
        v[u] = *reinterpret_cast<unsigned short*>(&hv);
    }
    *(ushort4*)((unsigned short*)hbT + (size_t)c * N + rbase + part * 4) =
        make_ushort4(v[0], v[1], v[2], v[3]);
}

// ---------------------------------------------------------------------------
// Kernel 2: the big one. grid = (128 row-tiles, NSPLIT j-chunks), 256 threads.
// Wave w owns rows r*64 + w*16 .. +15.  Per 32-j step:
//   - lane loads adj[i][j0+quad*8 .. +8)  (int4 x2; 16 rows x 128B contiguous)
//   - computes p = adj ? exp(leakyrelu(s1_i + s2_j)) : 0 in fp32, rounds to
//     bf16 directly into the 16x16x32 A-fragment (A[m=lane&15][k=quad*8+j])
//   - B-fragments: 16B contiguous loads from hbT (L2-resident)
//   - 4 MFMAs accumulate 16x64 out-tile; zpart accumulates row sums
// Partials (sum p*h, sum p) go to workspace; combined by kernel 3.
// ---------------------------------------------------------------------------
__global__ __launch_bounds__(256) void k2_attn(
    const int* __restrict__ adj,
    const float* __restrict__ s1, const float* __restrict__ s2,
    const unsigned short* __restrict__ hbT,
    float* __restrict__ pAcc, float* __restrict__ pZ)
{
    const int r   = blockIdx.x;          // row tile: 64 rows
    const int s   = blockIdx.y;          // j chunk
    const int tid = threadIdx.x;
    const int w    = tid >> 6;
    const int lane = tid & 63;
    const int row16 = lane & 15;
    const int quad  = lane >> 4;

    const int i = r * 64 + w * 16 + row16;
    const float s1i = s1[i];
    const int jbeg = s * JCHUNK;

    f32x4 acc0 = {0.f, 0.f, 0.f, 0.f};
    f32x4 acc1 = {0.f, 0.f, 0.f, 0.f};
    f32x4 acc2 = {0.f, 0.f, 0.f, 0.f};
    f32x4 acc3 = {0.f, 0.f, 0.f, 0.f};
    float zpart = 0.f;

    const int* adjrow = adj + (size_t)i * N;
    const short* hp = (const short*)hbT;

    for (int j0 = jbeg; j0 < jbeg + JCHUNK; j0 += 32) {
        const int jj = j0 + quad * 8;
        const int4 adj_a = *(const int4*)(adjrow + jj);
        const int4 adj_b = *(const int4*)(adjrow + jj + 4);
        const float4 s2a = *(const float4*)(s2 + jj);
        const float4 s2b = *(const float4*)(s2 + jj + 4);

        // B fragments (independent of p computation; compiler hoists loads)
        const short8 b0 = *(const short8*)(hp + (size_t)(row16 +  0) * N + jj);
        const short8 b1 = *(const short8*)(hp + (size_t)(row16 + 16) * N + jj);
        const short8 b2 = *(const short8*)(hp + (size_t)(row16 + 32) * N + jj);
        const short8 b3 = *(const short8*)(hp + (size_t)(row16 + 48) * N + jj);

        float s2v[8];
        s2v[0] = s2a.x; s2v[1] = s2a.y; s2v[2] = s2a.z; s2v[3] = s2a.w;
        s2v[4] = s2b.x; s2v[5] = s2b.y; s2v[6] = s2b.z; s2v[7] = s2b.w;
        int av[8];
        av[0] = adj_a.x; av[1] = adj_a.y; av[2] = adj_a.z; av[3] = adj_a.w;
        av[4] = adj_b.x; av[5] = adj_b.y; av[6] = adj_b.z; av[7] = adj_b.w;

        short8 afrag;
        #pragma unroll
        for (int j = 0; j < 8; ++j) {
            float e = s1i + s2v[j];
            e = e > 0.f ? e : ALPHA * e;
            float pv = (av[j] != 0) ? __expf(e) : 0.f;
            __hip_bfloat16 hv = __float2bfloat16(pv);
            zpart += __bfloat162float(hv);   // denominator matches bf16 numerator
            afrag[j] = *reinterpret_cast<short*>(&hv);
        }

        acc0 = __builtin_amdgcn_mfma_f32_16x16x32_bf16(afrag, b0, acc0, 0, 0, 0);
        acc1 = __builtin_amdgcn_mfma_f32_16x16x32_bf16(afrag, b1, acc1, 0, 0, 0);
        acc2 = __builtin_amdgcn_mfma_f32_16x16x32_bf16(afrag, b2, acc2, 0, 0, 0);
        acc3 = __builtin_amdgcn_mfma_f32_16x16x32_bf16(afrag, b3, acc3, 0, 0, 0);
    }

    // row-sum: reduce the 4 quads holding the same row
    zpart += __shfl_xor(zpart, 16, 64);
    zpart += __shfl_xor(zpart, 32, 64);
    if (quad == 0) pZ[(size_t)s * N + i] = zpart;

    // write partial out-tile; C/D layout: col=lane&15, row=quad*4+reg
    float* outp = pAcc + ((size_t)s * N + (size_t)r * 64 + w * 16) * FOUT;
    #pragma unroll
    for (int reg = 0; reg < 4; ++reg) {
        const int row = quad * 4 + reg;
        outp[row * FOUT + ( 0 + row16)] = acc0[reg];
        outp[row * FOUT + (16 + row16)] = acc1[reg];
        outp[row * FOUT + (32 + row16)] = acc2[reg];
        outp[row * FOUT + (48 + row16)] = acc3[reg];
    }
}

// ---------------------------------------------------------------------------
// Kernel 3: out[i][f] = sum_s pAcc[s][i][f] / sum_s pZ[s][i]
// ---------------------------------------------------------------------------
__global__ __launch_bounds__(256) void k3_combine(
    const float* __restrict__ pAcc, const float* __restrict__ pZ,
    float* __restrict__ out)
{
    const int idx = blockIdx.x * 256 + threadIdx.x;   // i*64 + f
    const int i = idx >> 6;
    float num = 0.f, den = 0.f;
    #pragma unroll
    for (int s = 0; s < NSPLIT; ++s) {
        num += pAcc[(size_t)s * N * FOUT + idx];
        den += pZ[(size_t)s * N + i];
    }
    out[idx] = num / den;
}

// ---------------------------------------------------------------------------
extern "C" void kernel_launch(void* const* d_in, const int* in_sizes, int n_in,
                              void* d_out, int out_size, void* d_ws, size_t ws_size,
                              hipStream_t stream)
{
    const float* input = (const float*)d_in[0];
    const int*   adj   = (const int*)d_in[1];
    const float* W     = (const float*)d_in[2];
    const float* a     = (const float*)d_in[3];
    float* out = (float*)d_out;

    char* ws = (char*)d_ws;
    __hip_bfloat16* hbT = (__hip_bfloat16*)ws;               // 64*N*2 = 1 MB
    float* s1   = (float*)(ws + (size_t)FOUT * N * 2);       // 32 KB
    float* s2   = s1 + N;                                    // 32 KB
    float* pZ   = s2 + N;                                    // NSPLIT*N*4 = 128 KB
    float* pAcc = pZ + (size_t)NSPLIT * N;                   // NSPLIT*N*64*4 = 8 MB

    k1_proj<<<N / 16, 256, 0, stream>>>(input, W, a, hbT, s1, s2);

    dim3 g2(N / 64, NSPLIT);
    k2_attn<<<g2, 256, 0, stream>>>(adj, s1, s2, (const unsigned short*)hbT, pAcc, pZ);

    k3_combine<<<(N * FOUT) / 256, 256, 0, stream>>>(pAcc, pZ, out);
}

// Round 2
// 485.798 us; speedup vs baseline: 1.0098x; 1.0098x over previous
//
#include <hip/hip_runtime.h>
#include <hip/hip_bf16.h>

#define ALPHA 0.2f

constexpr int N    = 8192;
constexpr int FIN  = 512;
constexpr int FOUT = 64;
constexpr int NSPLIT = 8;            // R2: 4->8 for occupancy (22% -> ~44%)
constexpr int JCHUNK = N / NSPLIT;   // 1024

typedef __attribute__((ext_vector_type(8))) short short8;
typedef __attribute__((ext_vector_type(4))) float f32x4;

// ---------------------------------------------------------------------------
// Kernel 1: h = input @ W (fp32), fused s1/s2 + bf16 h^T write.
// R2: 8 rows/block (1024 blocks -> 16 waves/CU), 2 rows/wave, k-step 8 for MLP.
// ---------------------------------------------------------------------------
__global__ __launch_bounds__(256) void k1_proj(
    const float* __restrict__ input, const float* __restrict__ W,
    const float* __restrict__ a, __hip_bfloat16* __restrict__ hbT,
    float* __restrict__ s1, float* __restrict__ s2)
{
    __shared__ __hip_bfloat16 tile[8][64];
    const int tid  = threadIdx.x;
    const int col  = tid & 63;
    const int g    = tid >> 6;           // wave id, owns rows 2g, 2g+1
    const int rbase = blockIdx.x * 8;

    float acc[2] = {0.f, 0.f};
    const float* in0 = input + (size_t)(rbase + g * 2) * FIN;

    for (int k = 0; k < FIN; k += 8) {
        // 8 W loads + 4 x loads issued together -> more loads in flight
        float w[8];
        #pragma unroll
        for (int q = 0; q < 8; ++q) w[q] = W[(k + q) * FOUT + col];
        const float4 x0a = *(const float4*)(in0 + 0 * FIN + k);
        const float4 x0b = *(const float4*)(in0 + 0 * FIN + k + 4);
        const float4 x1a = *(const float4*)(in0 + 1 * FIN + k);
        const float4 x1b = *(const float4*)(in0 + 1 * FIN + k + 4);
        acc[0] = fmaf(x0a.w, w[3], fmaf(x0a.z, w[2], fmaf(x0a.y, w[1], fmaf(x0a.x, w[0], acc[0]))));
        acc[0] = fmaf(x0b.w, w[7], fmaf(x0b.z, w[6], fmaf(x0b.y, w[5], fmaf(x0b.x, w[4], acc[0]))));
        acc[1] = fmaf(x1a.w, w[3], fmaf(x1a.z, w[2], fmaf(x1a.y, w[1], fmaf(x1a.x, w[0], acc[1]))));
        acc[1] = fmaf(x1b.w, w[7], fmaf(x1b.z, w[6], fmaf(x1b.y, w[5], fmaf(x1b.x, w[4], acc[1]))));
    }

    const float a1c = a[col];
    const float a2c = a[FOUT + col];
    #pragma unroll
    for (int q = 0; q < 2; ++q) {
        float r1 = acc[q] * a1c;
        float r2 = acc[q] * a2c;
        #pragma unroll
        for (int off = 32; off >= 1; off >>= 1) {
            r1 += __shfl_xor(r1, off, 64);
            r2 += __shfl_xor(r2, off, 64);
        }
        if (col == 0) {
            s1[rbase + g * 2 + q] = r1;
            s2[rbase + g * 2 + q] = r2;
        }
        tile[g * 2 + q][col] = __float2bfloat16(acc[q]);
    }
    __syncthreads();

    // transpose write: hbT[c][rbase + part*4 + u], 8B stores; 128 active threads
    if (tid < 128) {
        const int c = tid >> 1, part = tid & 1;
        unsigned short v[4];
        #pragma unroll
        for (int u = 0; u < 4; ++u) {
            __hip_bfloat16 hv = tile[part * 4 + u][c];
            v[u] = *reinterpret_cast<unsigned short*>(&hv);
        }
        *(ushort4*)((unsigned short*)hbT + (size_t)c * N + rbase + part * 4) =
            make_ushort4(v[0], v[1], v[2], v[3]);
    }
}

// ---------------------------------------------------------------------------
// Kernel 2: grid = (128 row-tiles, NSPLIT j-chunks), 256 threads.
// R2: register double-buffer prefetch of adj + s2 (next 32-j step) so the HBM
// adj stream stays in flight during the exp/MFMA compute phase.
// ---------------------------------------------------------------------------
__global__ __launch_bounds__(256) void k2_attn(
    const int* __restrict__ adj,
    const float* __restrict__ s1, const float* __restrict__ s2,
    const unsigned short* __restrict__ hbT,
    float* __restrict__ pAcc, float* __restrict__ pZ)
{
    const int r   = blockIdx.x;          // row tile: 64 rows
    const int s   = blockIdx.y;          // j chunk
    const int tid = threadIdx.x;
    const int w    = tid >> 6;
    const int lane = tid & 63;
    const int row16 = lane & 15;
    const int quad  = lane >> 4;

    const int i = r * 64 + w * 16 + row16;
    const float s1i = s1[i];
    const int jbeg = s * JCHUNK;
    const int jend = jbeg + JCHUNK;

    f32x4 acc0 = {0.f, 0.f, 0.f, 0.f};
    f32x4 acc1 = {0.f, 0.f, 0.f, 0.f};
    f32x4 acc2 = {0.f, 0.f, 0.f, 0.f};
    f32x4 acc3 = {0.f, 0.f, 0.f, 0.f};
    float zpart = 0.f;

    const int* adjrow = adj + (size_t)i * N;
    const short* hp = (const short*)hbT;

    // prime the pipeline
    {
        const int jj = jbeg + quad * 8;
        // fallthrough into loop below via cur registers
    }
    int jj0 = jbeg + quad * 8;
    int4   cA  = *(const int4*)(adjrow + jj0);
    int4   cB  = *(const int4*)(adjrow + jj0 + 4);
    float4 cSa = *(const float4*)(s2 + jj0);
    float4 cSb = *(const float4*)(s2 + jj0 + 4);

    for (int j0 = jbeg; j0 < jend; j0 += 32) {
        // ---- prefetch next step (clamped; redundant on last iter) ----
        const int jn = ((j0 + 32 < jend) ? (j0 + 32) : jbeg) + quad * 8;
        const int4   nA  = *(const int4*)(adjrow + jn);
        const int4   nB  = *(const int4*)(adjrow + jn + 4);
        const float4 nSa = *(const float4*)(s2 + jn);
        const float4 nSb = *(const float4*)(s2 + jn + 4);

        const int jj = j0 + quad * 8;

        // B fragments: L2-resident hbT, 16B contiguous
        const short8 b0 = *(const short8*)(hp + (size_t)(row16 +  0) * N + jj);
        const short8 b1 = *(const short8*)(hp + (size_t)(row16 + 16) * N + jj);
        const short8 b2 = *(const short8*)(hp + (size_t)(row16 + 32) * N + jj);
        const short8 b3 = *(const short8*)(hp + (size_t)(row16 + 48) * N + jj);

        float s2v[8];
        s2v[0] = cSa.x; s2v[1] = cSa.y; s2v[2] = cSa.z; s2v[3] = cSa.w;
        s2v[4] = cSb.x; s2v[5] = cSb.y; s2v[6] = cSb.z; s2v[7] = cSb.w;
        int av[8];
        av[0] = cA.x; av[1] = cA.y; av[2] = cA.z; av[3] = cA.w;
        av[4] = cB.x; av[5] = cB.y; av[6] = cB.z; av[7] = cB.w;

        short8 afrag;
        #pragma unroll
        for (int j = 0; j < 8; ++j) {
            float e = s1i + s2v[j];
            e = fmaxf(e, ALPHA * e);             // leakyrelu (valid both signs)
            float pv = (av[j] != 0) ? __expf(e) : 0.f;
            __hip_bfloat16 hv = __float2bfloat16(pv);
            zpart += __bfloat162float(hv);       // denominator matches bf16 numerator
            afrag[j] = *reinterpret_cast<short*>(&hv);
        }

        acc0 = __builtin_amdgcn_mfma_f32_16x16x32_bf16(afrag, b0, acc0, 0, 0, 0);
        acc1 = __builtin_amdgcn_mfma_f32_16x16x32_bf16(afrag, b1, acc1, 0, 0, 0);
        acc2 = __builtin_amdgcn_mfma_f32_16x16x32_bf16(afrag, b2, acc2, 0, 0, 0);
        acc3 = __builtin_amdgcn_mfma_f32_16x16x32_bf16(afrag, b3, acc3, 0, 0, 0);

        cA = nA; cB = nB; cSa = nSa; cSb = nSb;
    }

    // row-sum: reduce the 4 quads holding the same row
    zpart += __shfl_xor(zpart, 16, 64);
    zpart += __shfl_xor(zpart, 32, 64);
    if (quad == 0) pZ[(size_t)s * N + i] = zpart;

    // write partial out-tile; C/D layout: col=lane&15, row=quad*4+reg
    float* outp = pAcc + ((size_t)s * N + (size_t)r * 64 + w * 16) * FOUT;
    #pragma unroll
    for (int reg = 0; reg < 4; ++reg) {
        const int row = quad * 4 + reg;
        outp[row * FOUT + ( 0 + row16)] = acc0[reg];
        outp[row * FOUT + (16 + row16)] = acc1[reg];
        outp[row * FOUT + (32 + row16)] = acc2[reg];
        outp[row * FOUT + (48 + row16)] = acc3[reg];
    }
}

// ---------------------------------------------------------------------------
// Kernel 3: out[i][f] = sum_s pAcc[s][i][f] / sum_s pZ[s][i]
// ---------------------------------------------------------------------------
__global__ __launch_bounds__(256) void k3_combine(
    const float* __restrict__ pAcc, const float* __restrict__ pZ,
    float* __restrict__ out)
{
    const int idx = blockIdx.x * 256 + threadIdx.x;   // i*64 + f
    const int i = idx >> 6;
    float num = 0.f, den = 0.f;
    #pragma unroll
    for (int s = 0; s < NSPLIT; ++s) {
        num += pAcc[(size_t)s * N * FOUT + idx];
        den += pZ[(size_t)s * N + i];
    }
    out[idx] = num / den;
}

// ---------------------------------------------------------------------------
extern "C" void kernel_launch(void* const* d_in, const int* in_sizes, int n_in,
                              void* d_out, int out_size, void* d_ws, size_t ws_size,
                              hipStream_t stream)
{
    const float* input = (const float*)d_in[0];
    const int*   adj   = (const int*)d_in[1];
    const float* W     = (const float*)d_in[2];
    const float* a     = (const float*)d_in[3];
    float* out = (float*)d_out;

    char* ws = (char*)d_ws;
    __hip_bfloat16* hbT = (__hip_bfloat16*)ws;               // 64*N*2 = 1 MB
    float* s1   = (float*)(ws + (size_t)FOUT * N * 2);       // 32 KB
    float* s2   = s1 + N;                                    // 32 KB
    float* pZ   = s2 + N;                                    // NSPLIT*N*4 = 256 KB
    float* pAcc = pZ + (size_t)NSPLIT * N;                   // NSPLIT*N*64*4 = 16 MB

    k1_proj<<<N / 8, 256, 0, stream>>>(input, W, a, hbT, s1, s2);

    dim3 g2(N / 64, NSPLIT);
    k2_attn<<<g2, 256, 0, stream>>>(adj, s1, s2, (const unsigned short*)hbT, pAcc, pZ);

    k3_combine<<<(N * FOUT) / 256, 256, 0, stream>>>(pAcc, pZ, out);
}